// Round 5
// baseline (1545.754 us; speedup 1.0000x reference)
//
#include <hip/hip_runtime.h>
#include <math.h>

// Problem constants (from reference setup_inputs)
#define NB   1024   // batch
#define NS   512    // samples averaged (axis=1)
#define DIN  512    // layer-0 input dim
#define HID  64     // hidden
#define DOUT 4
#define GKB  8      // G+K = number of basis functions

// Knots, bit-exact vs reference: pts = float32(j-3) * float32(2/5) - 1.0f.
// Computed (not literal) so strict-IEEE f32 constant folding reproduces the
// exact numpy float32 values (literals like -1.8f differ in the last ulp).
__device__ __forceinline__ float knot(int j) {
    return (float)(j - 3) * 0.4f - 1.0f;
}

// Cox–de Boor recursion, order K=3, 12 uniform knots -> 8 basis values.
// Mirrors the reference: left = (x-t[m])/(t[m+j]-t[m]), right = (t[m+j+1]-x)/(t[m+j+1]-t[m+1])
__device__ __forceinline__ void bspline8(float x, float* __restrict__ B) {
    float Bt[11];
#pragma unroll
    for (int j = 0; j < 11; ++j)
        Bt[j] = (x >= knot(j) && x < knot(j + 1)) ? 1.0f : 0.0f;
#pragma unroll
    for (int ord = 1; ord <= 3; ++ord) {
#pragma unroll
        for (int m = 0; m + ord < 11; ++m) {
            float dl = knot(m + ord) - knot(m);           // compile-time fold (f32)
            float dr = knot(m + ord + 1) - knot(m + 1);
            float left  = (x - knot(m)) / dl;
            float right = (knot(m + ord + 1) - x) / dr;
            Bt[m] = left * Bt[m] + right * Bt[m + 1];
        }
    }
#pragma unroll
    for (int g = 0; g < GKB; ++g) B[g] = Bt[g];
}

__device__ __forceinline__ float silu_f(float v) {
    return v / (1.0f + expf(-v));
}
__device__ __forceinline__ float softplus_f(float v) {
    return fmaxf(v, 0.0f) + log1pf(expf(-fabsf(v)));
}

// ---------------------------------------------------------------------------
// Kernel 0: fold ss0 into coef0 and transpose for coalesced layer-0 reads.
// coefT[i][o][g] = coef0[o][i][g] * ss0[o][i];  sbT[i][o] = sb0[o][i]
// ---------------------------------------------------------------------------
__global__ __launch_bounds__(256) void k_prep(
    const float* __restrict__ coef0, const float* __restrict__ ss0,
    const float* __restrict__ sb0,
    float* __restrict__ coefT, float* __restrict__ sbT) {
    int t = blockIdx.x * 256 + threadIdx.x;
    if (t < HID * DIN * GKB) {
        int g = t & 7, o = (t >> 3) & 63, i = t >> 9;
        coefT[t] = coef0[(o * DIN + i) * GKB + g] * ss0[o * DIN + i];
    }
    if (t < HID * DIN) {
        int o = t & 63, i = t >> 6;
        sbT[t] = sb0[o * DIN + i];
    }
}

// ---------------------------------------------------------------------------
// Kernel 1: h[n,:] = mean over s of x[n,s,:]; fused silu(h) and B-spline basis.
// One block per n. 256 threads: 128 float4-columns x 2 s-halves.
// unroll 8: 8 outstanding float4 loads/thread -> ~8 KB in flight per wave,
// 16 waves/CU covers ~900cy HBM latency at ~10 B/cy/CU with large margin.
// ---------------------------------------------------------------------------
__global__ __launch_bounds__(256) void k_mean_basis(
    const float* __restrict__ x,
    float* __restrict__ silu_ws,   // [NB][DIN]
    float* __restrict__ bs_ws) {   // [NB][DIN][8]
    int n = blockIdx.x;
    int t = threadIdx.x;
    int c = t & 127;        // float4 column group: i = 4c..4c+3
    int half = t >> 7;      // s-half

    const float4* xr = reinterpret_cast<const float4*>(x + (size_t)n * NS * DIN);
    float4 acc = make_float4(0.f, 0.f, 0.f, 0.f);
    int s0 = half * (NS / 2);
#pragma unroll 8
    for (int s = s0; s < s0 + NS / 2; ++s) {
        float4 v = xr[s * (DIN / 4) + c];
        acc.x += v.x; acc.y += v.y; acc.z += v.z; acc.w += v.w;
    }

    __shared__ float4 sm[128];
    if (half) sm[c] = acc;
    __syncthreads();
    if (!half) {
        float4 o = sm[c];
        float hv[4];
        hv[0] = (acc.x + o.x) * (1.0f / NS);
        hv[1] = (acc.y + o.y) * (1.0f / NS);
        hv[2] = (acc.z + o.z) * (1.0f / NS);
        hv[3] = (acc.w + o.w) * (1.0f / NS);

        float sil[4];
        float B[4][GKB];
#pragma unroll
        for (int k = 0; k < 4; ++k) {
            sil[k] = silu_f(hv[k]);
            bspline8(hv[k], B[k]);
        }
        reinterpret_cast<float4*>(silu_ws)[n * 128 + c] =
            make_float4(sil[0], sil[1], sil[2], sil[3]);

        float4* bw = reinterpret_cast<float4*>(bs_ws + (size_t)n * DIN * GKB + (size_t)c * 32);
#pragma unroll
        for (int k = 0; k < 4; ++k) {
            bw[k * 2 + 0] = make_float4(B[k][0], B[k][1], B[k][2], B[k][3]);
            bw[k * 2 + 1] = make_float4(B[k][4], B[k][5], B[k][6], B[k][7]);
        }
    }
}

// ---------------------------------------------------------------------------
// Kernel 2: layer 0 (512 -> 64).
// 256 blocks x 512 threads. thread = (o in 64, n_local in 4, i-half in 2).
// h1[n][o] = sum_i silu[n,i]*sbT[i,o] + sum_g Bs[n,i,g]*coefT[i,o,g]
// ---------------------------------------------------------------------------
__global__ __launch_bounds__(512) void k_layer0(
    const float* __restrict__ silu_ws, const float* __restrict__ bs_ws,
    const float* __restrict__ coefT, const float* __restrict__ sbT,
    float* __restrict__ h1) {     // [NB][HID]
    int t = threadIdx.x;
    int o  = t & 63;
    int nl = (t >> 6) & 3;
    int ih = t >> 8;
    int n = blockIdx.x * 4 + nl;

    const float* bsn = bs_ws + (size_t)n * DIN * GKB;
    const float* sn  = silu_ws + (size_t)n * DIN;

    float acc = 0.f;
    int i0 = ih * (DIN / 2);
    for (int i = i0; i < i0 + DIN / 2; ++i) {
        float su = sn[i];                                         // broadcast (wave-uniform)
        float4 b0 = *reinterpret_cast<const float4*>(bsn + i * 8);      // broadcast
        float4 b1 = *reinterpret_cast<const float4*>(bsn + i * 8 + 4);  // broadcast
        const float4* cp = reinterpret_cast<const float4*>(coefT + (size_t)i * 512 + o * 8);
        float4 c0 = cp[0], c1 = cp[1];                            // coalesced (32B/lane)
        acc += su * sbT[i * 64 + o];                              // coalesced (4B/lane)
        acc += b0.x * c0.x + b0.y * c0.y + b0.z * c0.z + b0.w * c0.w
             + b1.x * c1.x + b1.y * c1.y + b1.z * c1.z + b1.w * c1.w;
    }

    __shared__ float red[512];
    red[t] = acc;
    __syncthreads();
    if (ih == 0) h1[n * HID + o] = acc + red[t + 256];
}

// ---------------------------------------------------------------------------
// Kernel 3: layers 1 (64->4), 2 (4->4), softplus, transpose-out.
// 2 threads per n (i-halves of layer 1), shfl reduce.
// ---------------------------------------------------------------------------
__global__ __launch_bounds__(256) void k_tail(
    const float* __restrict__ h1,
    const float* __restrict__ coef1, const float* __restrict__ sb1, const float* __restrict__ ss1,
    const float* __restrict__ coef2, const float* __restrict__ sb2, const float* __restrict__ ss2,
    float* __restrict__ out) {
    int tid = blockIdx.x * 256 + threadIdx.x;   // 0..2047
    int n = tid >> 1;
    int half = tid & 1;
    if (n >= NB) return;

    const float* hn = h1 + n * HID;
    float o1[4] = {0.f, 0.f, 0.f, 0.f};
    int i0 = half * (HID / 2);
    for (int i = i0; i < i0 + HID / 2; ++i) {
        float v = hn[i];
        float B[GKB];
        bspline8(v, B);
        float sil = silu_f(v);
#pragma unroll
        for (int o = 0; o < 4; ++o) {
            const float* cp = coef1 + (o * HID + i) * GKB;
            float s = 0.f;
#pragma unroll
            for (int g = 0; g < GKB; ++g) s += B[g] * cp[g];
            o1[o] += sil * sb1[o * HID + i] + ss1[o * HID + i] * s;
        }
    }
#pragma unroll
    for (int o = 0; o < 4; ++o) o1[o] += __shfl_xor(o1[o], 1);

    // layer 2 (both lanes of the pair compute; lane 0 writes)
    float o2[4] = {0.f, 0.f, 0.f, 0.f};
#pragma unroll
    for (int i = 0; i < 4; ++i) {
        float v = o1[i];
        float B[GKB];
        bspline8(v, B);
        float sil = silu_f(v);
#pragma unroll
        for (int o = 0; o < 4; ++o) {
            const float* cp = coef2 + (o * 4 + i) * GKB;
            float s = 0.f;
#pragma unroll
            for (int g = 0; g < GKB; ++g) s += B[g] * cp[g];
            o2[o] += sil * sb2[o * 4 + i] + ss2[o * 4 + i] * s;
        }
    }
    if (half == 0) {
#pragma unroll
        for (int c = 0; c < 4; ++c) out[c * NB + n] = softplus_f(o2[c]);
    }
}

// ---------------------------------------------------------------------------
extern "C" void kernel_launch(void* const* d_in, const int* in_sizes, int n_in,
                              void* d_out, int out_size, void* d_ws, size_t ws_size,
                              hipStream_t stream) {
    const float* x     = (const float*)d_in[0];
    const float* coef0 = (const float*)d_in[1];
    const float* sb0   = (const float*)d_in[2];
    const float* ss0   = (const float*)d_in[3];
    const float* coef1 = (const float*)d_in[4];
    const float* sb1   = (const float*)d_in[5];
    const float* ss1   = (const float*)d_in[6];
    const float* coef2 = (const float*)d_in[7];
    const float* sb2   = (const float*)d_in[8];
    const float* ss2   = (const float*)d_in[9];
    float* out = (float*)d_out;

    // Workspace layout (floats): ~20.3 MB total
    float* silu_ws = (float*)d_ws;                         // NB*DIN          = 524288
    float* bs_ws   = silu_ws + NB * DIN;                   // NB*DIN*8        = 4194304
    float* coefT   = bs_ws + (size_t)NB * DIN * GKB;       // HID*DIN*8       = 262144
    float* sbT     = coefT + HID * DIN * GKB;              // DIN*HID         = 32768
    float* h1      = sbT + DIN * HID;                      // NB*HID          = 65536

    k_prep<<<(HID * DIN * GKB + 255) / 256, 256, 0, stream>>>(coef0, ss0, sb0, coefT, sbT);
    k_mean_basis<<<NB, 256, 0, stream>>>(x, silu_ws, bs_ws);
    k_layer0<<<NB / 4, 512, 0, stream>>>(silu_ws, bs_ws, coefT, sbT, h1);
    k_tail<<<(2 * NB + 255) / 256, 256, 0, stream>>>(h1, coef1, sb1, ss1, coef2, sb2, ss2, out);
}